// Round 3
// baseline (363.956 us; speedup 1.0000x reference)
//
#include <hip/hip_runtime.h>
#include <math.h>

// LSTM: N=32768 seqs, T=600, H=5, input dim 1.
// 4 lanes per sequence: lane%4 = gate type (0:i, 1:f, 2:g, 3:o), each lane owns
// 5 gate rows of its type. Gate exchange = 4 uniform DPP quad_perm broadcasts
// per hidden unit (no cndmask role-selects). All 4 lanes redundantly update
// c,h (wave-wide issue cost is identical; avoids h re-broadcast).
// 32768 seqs * 4 lanes = 2048 waves = 2 waves/SIMD chip-wide -> TLP hides
// dependent-chain latency that capped R2 at VALUBusy=70%.
// Gate FMAs use explicit v_pk_fma_f32 (inline asm) to guarantee packing.

#define LOG2E 1.44269504088896340736f

typedef float v2f __attribute__((ext_vector_type(2)));

constexpr int T_ = 600;
constexpr int SEQ_PER_BLOCK = 16;   // 64 lanes / 4 lanes-per-seq
constexpr int TTILE = 64;
constexpr int LDS_STRIDE = 68;      // 68%32=4 -> only 2-way bank aliasing (free)

__device__ __forceinline__ float fast_rcp(float v)  { return __builtin_amdgcn_rcpf(v); }
__device__ __forceinline__ float fast_exp2(float v) { return __builtin_amdgcn_exp2f(v); }

// guaranteed packed fp32 fma: d = a*b + c on a VGPR pair
__device__ __forceinline__ v2f pk_fma(v2f a, v2f b, v2f c) {
    v2f d;
    asm("v_pk_fma_f32 %0, %1, %2, %3" : "=v"(d) : "v"(a), "v"(b), "v"(c));
    return d;
}

// broadcast lane (quad_base + L)'s value to all 4 lanes of the quad
template <int L>
__device__ __forceinline__ float quad_bcast(float v) {
    int r = __builtin_amdgcn_update_dpp(0, __float_as_int(v), L * 0x55, 0xF, 0xF, true);
    return __int_as_float(r);
}

__global__ __launch_bounds__(64, 2) void lstm_kernel(
    const float* __restrict__ x,
    const float* __restrict__ w_ih,   // (20,1)
    const float* __restrict__ w_hh,   // (20,5)
    const float* __restrict__ b_ih,   // (20,)
    const float* __restrict__ b_hh,   // (20,)
    const float* __restrict__ fc_w,   // (15,5)
    const float* __restrict__ fc_b,   // (15,)
    const float* __restrict__ out_w,  // (1,15)
    const float* __restrict__ out_b,  // (1,)
    float* __restrict__ out)          // (N,1)
{
    __shared__ float xs[SEQ_PER_BLOCK * LDS_STRIDE];

    const int lane = threadIdx.x;   // 0..63
    const int s    = lane >> 2;     // local sequence 0..15
    const int gt   = lane & 3;      // gate type: 0 i, 1 f, 2 g, 3 o
    const int seq  = blockIdx.x * SEQ_PER_BLOCK + s;

    // ---- per-lane weights: 5 rows of one gate type, rows packed (0,1),(2,3),4 ----
    v2f wih01, wih23, bb01, bb23, whh01[5], whh23[5];
    float wih4, bb4, whh4[5];
    {
        const int r0 = gt * 5 + 0, r1 = gt * 5 + 1, r2 = gt * 5 + 2,
                  r3 = gt * 5 + 3, r4 = gt * 5 + 4;
        wih01 = (v2f){ w_ih[r0], w_ih[r1] };
        wih23 = (v2f){ w_ih[r2], w_ih[r3] };
        wih4  = w_ih[r4];
        bb01  = (v2f){ b_ih[r0] + b_hh[r0], b_ih[r1] + b_hh[r1] };
        bb23  = (v2f){ b_ih[r2] + b_hh[r2], b_ih[r3] + b_hh[r3] };
        bb4   = b_ih[r4] + b_hh[r4];
#pragma unroll
        for (int k = 0; k < 5; ++k) {
            whh01[k] = (v2f){ w_hh[r0 * 5 + k], w_hh[r1 * 5 + k] };
            whh23[k] = (v2f){ w_hh[r2 * 5 + k], w_hh[r3 * 5 + k] };
            whh4[k]  = w_hh[r4 * 5 + k];
        }
    }
    // activation constants: gt==2 (g) -> tanh = 2*sig(2x)-1; else sigmoid
    const float S = (gt == 2) ? (-2.0f * LOG2E) : (-LOG2E);
    const float A = (gt == 2) ? 2.0f : 1.0f;
    const float B = (gt == 2) ? -1.0f : 0.0f;

    float h[5] = {0.f, 0.f, 0.f, 0.f, 0.f};
    float c[5] = {0.f, 0.f, 0.f, 0.f, 0.f};

    const float* xblk = x + (size_t)(blockIdx.x * SEQ_PER_BLOCK) * T_;

    auto step = [&](float xt) {
        // ---- 5 gate pre-activations of this lane's type ----
        const v2f x2 = (v2f){ xt, xt };
        v2f g01 = pk_fma(x2, wih01, bb01);
        v2f g23 = pk_fma(x2, wih23, bb23);
        float g4 = fmaf(xt, wih4, bb4);
#pragma unroll
        for (int k = 0; k < 5; ++k) {
            const v2f hk = (v2f){ h[k], h[k] };
            g01 = pk_fma(hk, whh01[k], g01);
            g23 = pk_fma(hk, whh23[k], g23);
            g4  = fmaf(h[k], whh4[k], g4);
        }
        // ---- activations: act = A*rcp(1+2^(g*S)) + B ----
        float gg[5] = { g01.x, g01.y, g23.x, g23.y, g4 };
        float act[5];
#pragma unroll
        for (int p = 0; p < 5; ++p) {
            const float r = fast_rcp(1.0f + fast_exp2(gg[p] * S));
            act[p] = fmaf(r, A, B);
        }
        // ---- quad broadcast + redundant state update ----
#pragma unroll
        for (int k = 0; k < 5; ++k) {
            const float iv = quad_bcast<0>(act[k]);
            const float fv = quad_bcast<1>(act[k]);
            const float gv = quad_bcast<2>(act[k]);
            const float ov = quad_bcast<3>(act[k]);
            c[k] = fmaf(fv, c[k], iv * gv);
            const float rr = fast_rcp(1.0f + fast_exp2(c[k] * (-2.0f * LOG2E)));
            h[k] = ov * fmaf(rr, 2.0f, -1.0f);   // o * tanh(c)
        }
    };

    const int rrow = lane >> 4;         // 0..3
    const int ccol = (lane & 15) << 2;  // 0,4,...,60

    for (int t0 = 0; t0 < T_; t0 += TTILE) {
        __syncthreads();
        // stage 16 rows x up-to-64 cols, coalesced float4 loads
#pragma unroll
        for (int it = 0; it < 4; ++it) {
            const int r = it * 4 + rrow;
            if (t0 + ccol < T_) {
                const float4 v = *(const float4*)(xblk + (size_t)r * T_ + (t0 + ccol));
                *(float4*)&xs[r * LDS_STRIDE + ccol] = v;
            }
        }
        __syncthreads();

        const int steps = min(TTILE, T_ - t0); // 64 or 24
        const float* xr = &xs[s * LDS_STRIDE];
        for (int tt = 0; tt < steps; tt += 4) {
            const float4 xv4 = *(const float4*)&xr[tt];
            step(xv4.x);
            step(xv4.y);
            step(xv4.z);
            step(xv4.w);
        }
    }

    // ---- head: hid = h@fc_w.T + fc_b ; out = sigmoid(hid@out_w.T + out_b) ----
    if (gt == 0) {
        float acc = out_b[0];
#pragma unroll
        for (int j = 0; j < 15; ++j) {
            float hid = fc_b[j];
#pragma unroll
            for (int k = 0; k < 5; ++k) hid = fmaf(h[k], fc_w[j * 5 + k], hid);
            acc = fmaf(hid, out_w[j], acc);
        }
        out[seq] = fast_rcp(1.0f + fast_exp2(-acc * LOG2E));
    }
}

extern "C" void kernel_launch(void* const* d_in, const int* in_sizes, int n_in,
                              void* d_out, int out_size, void* d_ws, size_t ws_size,
                              hipStream_t stream) {
    const float* x    = (const float*)d_in[0];
    const float* w_ih = (const float*)d_in[1];
    const float* w_hh = (const float*)d_in[2];
    const float* b_ih = (const float*)d_in[3];
    const float* b_hh = (const float*)d_in[4];
    const float* fc_w = (const float*)d_in[5];
    const float* fc_b = (const float*)d_in[6];
    const float* out_w = (const float*)d_in[7];
    const float* out_b = (const float*)d_in[8];
    float* out = (float*)d_out;

    const int N = in_sizes[0] / T_;             // 32768
    const int grid = N / SEQ_PER_BLOCK;         // 2048 blocks -> 2048 waves -> 2/SIMD
    hipLaunchKernelGGL(lstm_kernel, dim3(grid), dim3(64), 0, stream,
                       x, w_ih, w_hh, b_ih, b_hh, fc_w, fc_b, out_w, out_b, out);
}

// Round 4
// 301.637 us; speedup vs baseline: 1.2066x; 1.2066x over previous
//
#include <hip/hip_runtime.h>
#include <math.h>

// LSTM: N=32768 seqs, T=600, H=5, input dim 1.
// 2 lanes/seq (R2 layout, best static instr/seq), cleaned codegen:
//  - gate weights pre-scaled by -log2e (sigmoid rows) / -2log2e (g rows):
//    act = rcp(1+exp2(gate)) with no per-step scale mul
//  - gate rows packed {lo,hi} as float2 -> v_pk_fma_f32 (no inline asm)
//  - DPP swap with old=src (single v_mov_b32_dpp, no zero-mov)
// Even lane (half=0): lo = i rows 0..4, hi = g rows 10..14 (tanh).
// Odd  lane (half=1): lo = f rows 5..9, hi = o rows 15..19.
// Block = 64 = 1 wave = 32 seqs; grid = 1024 -> 1 wave/SIMD chip-wide.

#define LOG2E 1.44269504088896340736f

typedef float v2f __attribute__((ext_vector_type(2)));

constexpr int T_ = 600;
constexpr int SEQ_PER_BLOCK = 32;
constexpr int TTILE = 64;
constexpr int LDS_STRIDE = 68;   // 68%32=4 -> 2-way bank aliasing only (free)

__device__ __forceinline__ float fast_rcp(float v)  { return __builtin_amdgcn_rcpf(v); }
__device__ __forceinline__ float fast_exp2(float v) { return __builtin_amdgcn_exp2f(v); }

// swap with lane^1 via DPP quad_perm [1,0,3,2]; all lanes active -> old unused
__device__ __forceinline__ float dpp_swap1(float v) {
    const int x = __float_as_int(v);
    return __int_as_float(__builtin_amdgcn_update_dpp(x, x, 0xB1, 0xF, 0xF, false));
}

__global__ __launch_bounds__(64, 1) void lstm_kernel(
    const float* __restrict__ x,
    const float* __restrict__ w_ih,   // (20,1)
    const float* __restrict__ w_hh,   // (20,5)
    const float* __restrict__ b_ih,   // (20,)
    const float* __restrict__ b_hh,   // (20,)
    const float* __restrict__ fc_w,   // (15,5)
    const float* __restrict__ fc_b,   // (15,)
    const float* __restrict__ out_w,  // (1,15)
    const float* __restrict__ out_b,  // (1,)
    float* __restrict__ out)          // (N,1)
{
    __shared__ float xs[SEQ_PER_BLOCK * LDS_STRIDE];

    const int lane = threadIdx.x;     // 0..63
    const int s    = lane >> 1;       // local sequence 0..31
    const int half = lane & 1;        // 0: i/g rows, 1: f/o rows
    const int seq  = blockIdx.x * SEQ_PER_BLOCK + s;

    // ---- pre-scaled per-lane weights, rows paired {lo, hi} ----
    const float slo = -LOG2E;                          // i / f: sigmoid
    const float shi = half ? -LOG2E : -2.0f * LOG2E;   // o: sigmoid, g: tanh
    v2f wih2[5], bb2[5], whh2[5][5];
#pragma unroll
    for (int p = 0; p < 5; ++p) {
        const int rlo = half * 5 + p;       // i (h0) / f (h1)
        const int rhi = 10 + half * 5 + p;  // g (h0) / o (h1)
        wih2[p] = (v2f){ w_ih[rlo] * slo, w_ih[rhi] * shi };
        bb2[p]  = (v2f){ (b_ih[rlo] + b_hh[rlo]) * slo,
                         (b_ih[rhi] + b_hh[rhi]) * shi };
#pragma unroll
        for (int k = 0; k < 5; ++k)
            whh2[p][k] = (v2f){ w_hh[rlo * 5 + k] * slo, w_hh[rhi * 5 + k] * shi };
    }
    const float Ahi = half ? 1.0f : 2.0f;    // hi-row activation: fma(r,A,B)
    const float Bhi = half ? 0.0f : -1.0f;   // tanh = 2r-1, sigmoid = r

    float h[5] = {0.f, 0.f, 0.f, 0.f, 0.f};
    float c[5] = {0.f, 0.f, 0.f, 0.f, 0.f};

    const float* xblk = x + (size_t)(blockIdx.x * SEQ_PER_BLOCK) * T_;

    auto step = [&](float xt) {
        // ---- gate pre-activations (pre-scaled space), packed fp32 ----
        const v2f x2 = (v2f){ xt, xt };
        v2f g2[5];
#pragma unroll
        for (int p = 0; p < 5; ++p) g2[p] = x2 * wih2[p] + bb2[p];
#pragma unroll
        for (int k = 0; k < 5; ++k) {
            const v2f h2 = (v2f){ h[k], h[k] };
#pragma unroll
            for (int p = 0; p < 5; ++p) g2[p] += h2 * whh2[p][k];
        }
        // ---- activations: r = rcp(1+exp2(g)) (no scale mul needed) ----
        float actl[5], acth[5];
#pragma unroll
        for (int p = 0; p < 5; ++p) {
            actl[p] = fast_rcp(1.0f + fast_exp2(g2[p].x));                  // i or f
            acth[p] = fmaf(fast_rcp(1.0f + fast_exp2(g2[p].y)), Ahi, Bhi);  // g or o
        }
        // ---- exchange with partner lane (single-instr DPP) ----
        float sl[5], sh[5];
#pragma unroll
        for (int k = 0; k < 5; ++k) { sl[k] = dpp_swap1(actl[k]); sh[k] = dpp_swap1(acth[k]); }
        // ---- state update (both lanes redundantly) ----
#pragma unroll
        for (int k = 0; k < 5; ++k) {
            const float t0 = actl[k] * acth[k];   // h0: i*g, h1: f*o
            const float t1 = sl[k] * sh[k];       // h0: f*o, h1: i*g
            const float ig = half ? t1 : t0;
            const float fv = half ? actl[k] : sl[k];
            c[k] = fmaf(fv, c[k], ig);
            const float e  = fast_exp2(c[k] * (-2.0f * LOG2E));
            const float tc = fmaf(fast_rcp(1.0f + e), 2.0f, -1.0f);  // tanh(c)
            const float ov = half ? acth[k] : sh[k];
            h[k] = ov * tc;
        }
    };

    const int rrow = lane >> 4;         // 0..3
    const int ccol = (lane & 15) << 2;  // 0,4,...,60

    for (int t0 = 0; t0 < T_; t0 += TTILE) {
        __syncthreads();
        // stage 32 rows x up-to-64 cols, coalesced float4 loads
#pragma unroll
        for (int it = 0; it < 8; ++it) {
            const int r = it * 4 + rrow;
            if (t0 + ccol < T_) {
                const float4 v = *(const float4*)(xblk + (size_t)r * T_ + (t0 + ccol));
                *(float4*)&xs[r * LDS_STRIDE + ccol] = v;
            }
        }
        __syncthreads();

        const int steps = min(TTILE, T_ - t0); // 64 or 24
        const float* xr = &xs[s * LDS_STRIDE];
        for (int tt = 0; tt < steps; tt += 4) {
            const float4 xv4 = *(const float4*)&xr[tt];
            step(xv4.x);
            step(xv4.y);
            step(xv4.z);
            step(xv4.w);
        }
    }

    // ---- head: hid = h@fc_w.T + fc_b ; out = sigmoid(hid@out_w.T + out_b) ----
    if (half == 0) {
        float acc = out_b[0];
#pragma unroll
        for (int j = 0; j < 15; ++j) {
            float hid = fc_b[j];
#pragma unroll
            for (int k = 0; k < 5; ++k) hid = fmaf(h[k], fc_w[j * 5 + k], hid);
            acc = fmaf(hid, out_w[j], acc);
        }
        out[seq] = fast_rcp(1.0f + fast_exp2(-acc * LOG2E));
    }
}

extern "C" void kernel_launch(void* const* d_in, const int* in_sizes, int n_in,
                              void* d_out, int out_size, void* d_ws, size_t ws_size,
                              hipStream_t stream) {
    const float* x    = (const float*)d_in[0];
    const float* w_ih = (const float*)d_in[1];
    const float* w_hh = (const float*)d_in[2];
    const float* b_ih = (const float*)d_in[3];
    const float* b_hh = (const float*)d_in[4];
    const float* fc_w = (const float*)d_in[5];
    const float* fc_b = (const float*)d_in[6];
    const float* out_w = (const float*)d_in[7];
    const float* out_b = (const float*)d_in[8];
    float* out = (float*)d_out;

    const int N = in_sizes[0] / T_;             // 32768
    const int grid = N / SEQ_PER_BLOCK;         // 1024 blocks -> 1 wave/SIMD
    hipLaunchKernelGGL(lstm_kernel, dim3(grid), dim3(64), 0, stream,
                       x, w_ih, w_hh, b_ih, b_hh, fc_w, fc_b, out_w, out_b, out);
}

// Round 5
// 286.492 us; speedup vs baseline: 1.2704x; 1.0529x over previous
//
#include <hip/hip_runtime.h>
#include <math.h>

// LSTM: N=32768 seqs, T=600, H=5, input dim 1.
// 2 lanes/seq; trans-issue-bound (v_exp/v_rcp ~16cyc wave64). R5:
//  - paired reciprocals: rcp count 15 -> 8 per step (1 rcp + 3 mul per pair)
//  - g-row activation emits -2log2e*tanh(g) directly (A=-4log2e, B=2log2e);
//    c tracked in pre-scaled space -> exp2(c~) needs no scale mul
// Even lane (half=0): lo = i rows 0..4, hi = g rows 10..14 (tanh).
// Odd  lane (half=1): lo = f rows 5..9, hi = o rows 15..19.
// Block = 64 = 1 wave = 32 seqs; grid = 1024 -> 1 wave/SIMD chip-wide.

#define LOG2E 1.44269504088896340736f

typedef float v2f __attribute__((ext_vector_type(2)));

constexpr int T_ = 600;
constexpr int SEQ_PER_BLOCK = 32;
constexpr int TTILE = 64;
constexpr int LDS_STRIDE = 68;   // 68%32=4 -> 2-way bank aliasing only (free)

__device__ __forceinline__ float fast_rcp(float v)  { return __builtin_amdgcn_rcpf(v); }
__device__ __forceinline__ float fast_exp2(float v) { return __builtin_amdgcn_exp2f(v); }

// swap with lane^1 via DPP quad_perm [1,0,3,2]; all lanes active -> old unused
__device__ __forceinline__ float dpp_swap1(float v) {
    const int x = __float_as_int(v);
    return __int_as_float(__builtin_amdgcn_update_dpp(x, x, 0xB1, 0xF, 0xF, false));
}

__global__ __launch_bounds__(64, 1) void lstm_kernel(
    const float* __restrict__ x,
    const float* __restrict__ w_ih,   // (20,1)
    const float* __restrict__ w_hh,   // (20,5)
    const float* __restrict__ b_ih,   // (20,)
    const float* __restrict__ b_hh,   // (20,)
    const float* __restrict__ fc_w,   // (15,5)
    const float* __restrict__ fc_b,   // (15,)
    const float* __restrict__ out_w,  // (1,15)
    const float* __restrict__ out_b,  // (1,)
    float* __restrict__ out)          // (N,1)
{
    __shared__ float xs[SEQ_PER_BLOCK * LDS_STRIDE];

    const int lane = threadIdx.x;     // 0..63
    const int s    = lane >> 1;       // local sequence 0..31
    const int half = lane & 1;        // 0: i/g rows, 1: f/o rows
    const int seq  = blockIdx.x * SEQ_PER_BLOCK + s;

    // ---- pre-scaled per-lane weights, rows paired {lo, hi} ----
    const float slo = -LOG2E;                          // i / f: sigmoid
    const float shi = half ? -LOG2E : -2.0f * LOG2E;   // o: sigmoid, g: tanh (sig(2x))
    v2f wih2[5], bb2[5], whh2[5][5];
#pragma unroll
    for (int p = 0; p < 5; ++p) {
        const int rlo = half * 5 + p;       // i (h0) / f (h1)
        const int rhi = 10 + half * 5 + p;  // g (h0) / o (h1)
        wih2[p] = (v2f){ w_ih[rlo] * slo, w_ih[rhi] * shi };
        bb2[p]  = (v2f){ (b_ih[rlo] + b_hh[rlo]) * slo,
                         (b_ih[rhi] + b_hh[rhi]) * shi };
#pragma unroll
        for (int k = 0; k < 5; ++k)
            whh2[p][k] = (v2f){ w_hh[rlo * 5 + k] * slo, w_hh[rhi * 5 + k] * shi };
    }
    // hi-row output transform: h0 (g): acth = -2log2e * tanh(g)  (c~-space input)
    //                          h1 (o): acth = sigmoid (plain)
    const float Ahi = half ? 1.0f : (-4.0f * LOG2E);
    const float Bhi = half ? 0.0f : ( 2.0f * LOG2E);

    float h[5] = {0.f, 0.f, 0.f, 0.f, 0.f};
    float c[5] = {0.f, 0.f, 0.f, 0.f, 0.f};   // pre-scaled: c~ = -2log2e * c

    const float* xblk = x + (size_t)(blockIdx.x * SEQ_PER_BLOCK) * T_;

    auto step = [&](float xt) {
        // ---- gate pre-activations (pre-scaled space), packed fp32 ----
        const v2f x2 = (v2f){ xt, xt };
        v2f g2[5];
#pragma unroll
        for (int p = 0; p < 5; ++p) g2[p] = x2 * wih2[p] + bb2[p];
#pragma unroll
        for (int k = 0; k < 5; ++k) {
            const v2f h2 = (v2f){ h[k], h[k] };
#pragma unroll
            for (int p = 0; p < 5; ++p) g2[p] += h2 * whh2[p][k];
        }
        // ---- activations, paired rcp within each {lo,hi} pair ----
        float actl[5], acth[5];
#pragma unroll
        for (int p = 0; p < 5; ++p) {
            const float dl = 1.0f + fast_exp2(g2[p].x);
            const float dh = 1.0f + fast_exp2(g2[p].y);
            const float rp = fast_rcp(dl * dh);
            actl[p] = rp * dh;                          // sigmoid (i or f)
            acth[p] = fmaf(rp * dl, Ahi, Bhi);          // -2log2e*tanh(g) or sigmoid(o)
        }
        // ---- exchange with partner lane (single-instr DPP) ----
        float sl[5], sh[5];
#pragma unroll
        for (int k = 0; k < 5; ++k) { sl[k] = dpp_swap1(actl[k]); sh[k] = dpp_swap1(acth[k]); }
        // ---- state update in c~-space (both lanes redundantly) ----
        float d[5], ov[5];
#pragma unroll
        for (int k = 0; k < 5; ++k) {
            const float t0 = actl[k] * acth[k];   // h0: i*g~
            const float t1 = sl[k] * sh[k];       // h1: i*g~
            const float ig = half ? t1 : t0;
            const float fv = half ? actl[k] : sl[k];
            ov[k]          = half ? acth[k] : sh[k];
            c[k] = fmaf(fv, c[k], ig);
            d[k] = 1.0f + fast_exp2(c[k]);        // c already = -2log2e * c_true
        }
        // tanh(c_true) = 2*rcp(d)-1, rcps paired (0,1),(2,3),(4)
        {
            const float i01 = fast_rcp(d[0] * d[1]);
            const float i23 = fast_rcp(d[2] * d[3]);
            const float i4  = fast_rcp(d[4]);
            const float r0 = i01 * d[1], r1 = i01 * d[0];
            const float r2 = i23 * d[3], r3 = i23 * d[2];
            h[0] = ov[0] * fmaf(r0, 2.0f, -1.0f);
            h[1] = ov[1] * fmaf(r1, 2.0f, -1.0f);
            h[2] = ov[2] * fmaf(r2, 2.0f, -1.0f);
            h[3] = ov[3] * fmaf(r3, 2.0f, -1.0f);
            h[4] = ov[4] * fmaf(i4, 2.0f, -1.0f);
        }
    };

    const int rrow = lane >> 4;         // 0..3
    const int ccol = (lane & 15) << 2;  // 0,4,...,60

    for (int t0 = 0; t0 < T_; t0 += TTILE) {
        __syncthreads();
        // stage 32 rows x up-to-64 cols, coalesced float4 loads
#pragma unroll
        for (int it = 0; it < 8; ++it) {
            const int r = it * 4 + rrow;
            if (t0 + ccol < T_) {
                const float4 v = *(const float4*)(xblk + (size_t)r * T_ + (t0 + ccol));
                *(float4*)&xs[r * LDS_STRIDE + ccol] = v;
            }
        }
        __syncthreads();

        const int steps = min(TTILE, T_ - t0); // 64 or 24
        const float* xr = &xs[s * LDS_STRIDE];
        for (int tt = 0; tt < steps; tt += 4) {
            const float4 xv4 = *(const float4*)&xr[tt];
            step(xv4.x);
            step(xv4.y);
            step(xv4.z);
            step(xv4.w);
        }
    }

    // ---- head: hid = h@fc_w.T + fc_b ; out = sigmoid(hid@out_w.T + out_b) ----
    if (half == 0) {
        float acc = out_b[0];
#pragma unroll
        for (int j = 0; j < 15; ++j) {
            float hid = fc_b[j];
#pragma unroll
            for (int k = 0; k < 5; ++k) hid = fmaf(h[k], fc_w[j * 5 + k], hid);
            acc = fmaf(hid, out_w[j], acc);
        }
        out[seq] = fast_rcp(1.0f + fast_exp2(-acc * LOG2E));
    }
}

extern "C" void kernel_launch(void* const* d_in, const int* in_sizes, int n_in,
                              void* d_out, int out_size, void* d_ws, size_t ws_size,
                              hipStream_t stream) {
    const float* x    = (const float*)d_in[0];
    const float* w_ih = (const float*)d_in[1];
    const float* w_hh = (const float*)d_in[2];
    const float* b_ih = (const float*)d_in[3];
    const float* b_hh = (const float*)d_in[4];
    const float* fc_w = (const float*)d_in[5];
    const float* fc_b = (const float*)d_in[6];
    const float* out_w = (const float*)d_in[7];
    const float* out_b = (const float*)d_in[8];
    float* out = (float*)d_out;

    const int N = in_sizes[0] / T_;             // 32768
    const int grid = N / SEQ_PER_BLOCK;         // 1024 blocks -> 1 wave/SIMD
    hipLaunchKernelGGL(lstm_kernel, dim3(grid), dim3(64), 0, stream,
                       x, w_ih, w_hh, b_ih, b_hh, fc_w, fc_b, out_w, out_b, out);
}

// Round 6
// 280.179 us; speedup vs baseline: 1.2990x; 1.0225x over previous
//
#include <hip/hip_runtime.h>
#include <math.h>

// LSTM: N=32768 seqs, T=600, H=5, input dim 1.
// 2 lanes/seq. R6:
//  - amdgpu_waves_per_eu(1,1): 512-VGPR budget so the 70 weight VGPRs stay
//    register-resident (R5 VGPR_Count=68 < weight footprint => reloads)
//  - pair-broadcast DPP (quad_perm[0,0,2,2]/[1,1,3,3]) replaces swap+cndmask:
//    canonical i*g, f, o appear on BOTH lanes with zero selects
//  - explicit v_pk_fma_f32 for the 30-FMA gate matvec
// Even lane (half=0): lo = i rows, hi = g rows (tanh, c~-space output).
// Odd  lane (half=1): lo = f rows, hi = o rows (sigmoid).
// Block = 64 = 1 wave = 32 seqs; grid = 1024 -> 1 wave/SIMD chip-wide.

#define LOG2E 1.44269504088896340736f

typedef float v2f __attribute__((ext_vector_type(2)));

constexpr int T_ = 600;
constexpr int SEQ_PER_BLOCK = 32;
constexpr int TTILE = 64;
constexpr int LDS_STRIDE = 68;   // 68%32=4 -> 2-way bank aliasing only (free)

__device__ __forceinline__ float fast_rcp(float v)  { return __builtin_amdgcn_rcpf(v); }
__device__ __forceinline__ float fast_exp2(float v) { return __builtin_amdgcn_exp2f(v); }

// packed fp32 fma on VGPR pairs (compiles/ran in R3)
__device__ __forceinline__ v2f pk_fma(v2f a, v2f b, v2f c) {
    v2f d;
    asm("v_pk_fma_f32 %0, %1, %2, %3" : "=v"(d) : "v"(a), "v"(b), "v"(c));
    return d;
}

// broadcast even lane of each pair to both lanes: quad_perm [0,0,2,2] = 0xA0
// broadcast odd  lane of each pair to both lanes: quad_perm [1,1,3,3] = 0xF5
template <int CTRL>
__device__ __forceinline__ float dpp_q(float v) {
    const int x = __float_as_int(v);
    return __int_as_float(__builtin_amdgcn_update_dpp(x, x, CTRL, 0xF, 0xF, false));
}

__global__ __launch_bounds__(64, 1)
__attribute__((amdgpu_waves_per_eu(1, 1)))
void lstm_kernel(
    const float* __restrict__ x,
    const float* __restrict__ w_ih,   // (20,1)
    const float* __restrict__ w_hh,   // (20,5)
    const float* __restrict__ b_ih,   // (20,)
    const float* __restrict__ b_hh,   // (20,)
    const float* __restrict__ fc_w,   // (15,5)
    const float* __restrict__ fc_b,   // (15,)
    const float* __restrict__ out_w,  // (1,15)
    const float* __restrict__ out_b,  // (1,)
    float* __restrict__ out)          // (N,1)
{
    __shared__ float xs[SEQ_PER_BLOCK * LDS_STRIDE];

    const int lane = threadIdx.x;     // 0..63
    const int s    = lane >> 1;       // local sequence 0..31
    const int half = lane & 1;        // 0: i/g rows, 1: f/o rows
    const int seq  = blockIdx.x * SEQ_PER_BLOCK + s;

    // ---- pre-scaled per-lane weights, rows paired {lo, hi} ----
    const float slo = -LOG2E;                          // i / f: sigmoid
    const float shi = half ? -LOG2E : -2.0f * LOG2E;   // o: sigmoid, g: tanh (sig(2x))
    v2f wih2[5], bb2[5], whh2[5][5];
#pragma unroll
    for (int p = 0; p < 5; ++p) {
        const int rlo = half * 5 + p;       // i (h0) / f (h1)
        const int rhi = 10 + half * 5 + p;  // g (h0) / o (h1)
        wih2[p] = (v2f){ w_ih[rlo] * slo, w_ih[rhi] * shi };
        bb2[p]  = (v2f){ (b_ih[rlo] + b_hh[rlo]) * slo,
                         (b_ih[rhi] + b_hh[rhi]) * shi };
#pragma unroll
        for (int k = 0; k < 5; ++k)
            whh2[p][k] = (v2f){ w_hh[rlo * 5 + k] * slo, w_hh[rhi * 5 + k] * shi };
    }
    // hi-row output transform: h0 (g): acth = -2log2e*tanh(g) (c~-space)
    //                          h1 (o): acth = sigmoid (A=1,B=0)
    const float Ahi = half ? 1.0f : (-4.0f * LOG2E);
    const float Bhi = half ? 0.0f : ( 2.0f * LOG2E);

    float h[5] = {0.f, 0.f, 0.f, 0.f, 0.f};
    float c[5] = {0.f, 0.f, 0.f, 0.f, 0.f};   // c~ = -2log2e * c_true

    const float* xblk = x + (size_t)(blockIdx.x * SEQ_PER_BLOCK) * T_;

    auto step = [&](float xt) {
        // ---- gate pre-activations (pre-scaled space): 30 v_pk_fma_f32 ----
        const v2f x2 = (v2f){ xt, xt };
        v2f g2[5];
#pragma unroll
        for (int p = 0; p < 5; ++p) g2[p] = pk_fma(x2, wih2[p], bb2[p]);
#pragma unroll
        for (int k = 0; k < 5; ++k) {
            const v2f h2 = (v2f){ h[k], h[k] };
#pragma unroll
            for (int p = 0; p < 5; ++p) g2[p] = pk_fma(h2, whh2[p][k], g2[p]);
        }
        // ---- activations, paired rcp within each {lo,hi} pair ----
        float actl[5], acth[5];
#pragma unroll
        for (int p = 0; p < 5; ++p) {
            const float dl = 1.0f + fast_exp2(g2[p].x);
            const float dh = 1.0f + fast_exp2(g2[p].y);
            const float rp = fast_rcp(dl * dh);
            actl[p] = rp * dh;                   // sigmoid: i (h0) / f (h1)
            acth[p] = fmaf(rp * dl, Ahi, Bhi);   // g~ = -2L*tanh(g) (h0) / sigmoid o (h1)
        }
        // ---- canonical values on both lanes via pair-broadcast DPP ----
        // even lane holds i,g~ -> P = i*g~ valid there; odd lane holds f,o
        float d[5], oB[5];
#pragma unroll
        for (int k = 0; k < 5; ++k) {
            const float P  = actl[k] * acth[k];     // i*g~ on even lane (garbage on odd)
            const float PB = dpp_q<0xA0>(P);        // i*g~ on both
            const float fB = dpp_q<0xF5>(actl[k]);  // f on both
            oB[k]          = dpp_q<0xF5>(acth[k]);  // o on both
            c[k] = fmaf(fB, c[k], PB);
            d[k] = 1.0f + fast_exp2(c[k]);          // c~-space: = 1 + e^{-2c}
        }
        // tanh(c_true) = 2*rcp(d)-1, rcps paired (0,1),(2,3),(4)
        {
            const float i01 = fast_rcp(d[0] * d[1]);
            const float i23 = fast_rcp(d[2] * d[3]);
            const float i4  = fast_rcp(d[4]);
            const float r0 = i01 * d[1], r1 = i01 * d[0];
            const float r2 = i23 * d[3], r3 = i23 * d[2];
            h[0] = oB[0] * fmaf(r0, 2.0f, -1.0f);
            h[1] = oB[1] * fmaf(r1, 2.0f, -1.0f);
            h[2] = oB[2] * fmaf(r2, 2.0f, -1.0f);
            h[3] = oB[3] * fmaf(r3, 2.0f, -1.0f);
            h[4] = oB[4] * fmaf(i4, 2.0f, -1.0f);
        }
    };

    const int rrow = lane >> 4;         // 0..3
    const int ccol = (lane & 15) << 2;  // 0,4,...,60

    for (int t0 = 0; t0 < T_; t0 += TTILE) {
        __syncthreads();
        // stage 32 rows x up-to-64 cols, coalesced float4 loads
#pragma unroll
        for (int it = 0; it < 8; ++it) {
            const int r = it * 4 + rrow;
            if (t0 + ccol < T_) {
                const float4 v = *(const float4*)(xblk + (size_t)r * T_ + (t0 + ccol));
                *(float4*)&xs[r * LDS_STRIDE + ccol] = v;
            }
        }
        __syncthreads();

        const int steps = min(TTILE, T_ - t0); // 64 or 24
        const float* xr = &xs[s * LDS_STRIDE];
        for (int tt = 0; tt < steps; tt += 4) {
            const float4 xv4 = *(const float4*)&xr[tt];
            step(xv4.x);
            step(xv4.y);
            step(xv4.z);
            step(xv4.w);
        }
    }

    // ---- head: hid = h@fc_w.T + fc_b ; out = sigmoid(hid@out_w.T + out_b) ----
    if (half == 0) {
        float acc = out_b[0];
#pragma unroll
        for (int j = 0; j < 15; ++j) {
            float hid = fc_b[j];
#pragma unroll
            for (int k = 0; k < 5; ++k) hid = fmaf(h[k], fc_w[j * 5 + k], hid);
            acc = fmaf(hid, out_w[j], acc);
        }
        out[seq] = fast_rcp(1.0f + fast_exp2(-acc * LOG2E));
    }
}

extern "C" void kernel_launch(void* const* d_in, const int* in_sizes, int n_in,
                              void* d_out, int out_size, void* d_ws, size_t ws_size,
                              hipStream_t stream) {
    const float* x    = (const float*)d_in[0];
    const float* w_ih = (const float*)d_in[1];
    const float* w_hh = (const float*)d_in[2];
    const float* b_ih = (const float*)d_in[3];
    const float* b_hh = (const float*)d_in[4];
    const float* fc_w = (const float*)d_in[5];
    const float* fc_b = (const float*)d_in[6];
    const float* out_w = (const float*)d_in[7];
    const float* out_b = (const float*)d_in[8];
    float* out = (float*)d_out;

    const int N = in_sizes[0] / T_;             // 32768
    const int grid = N / SEQ_PER_BLOCK;         // 1024 blocks -> 1 wave/SIMD
    hipLaunchKernelGGL(lstm_kernel, dim3(grid), dim3(64), 0, stream,
                       x, w_ih, w_hh, b_ih, b_hh, fc_w, fc_b, out_w, out_b, out);
}